// Round 1
// baseline (2778.074 us; speedup 1.0000x reference)
//
#include <hip/hip_runtime.h>

#define BLK 256

constexpr int Bn = 4, Cn = 3, Hn = 1024, Wn = 1024;
constexpr int HW   = Hn * Wn;        // 1<<20
constexpr int BHW  = Bn * HW;        // 4,194,304
constexpr int BCHW = Bn * Cn * HW;   // 12,582,912
constexpr int MAX_ITERS = 4;

// ---------------- splat: scatter-add im0 by flow ----------------
__global__ __launch_bounds__(BLK) void splat_kernel(
    const float* __restrict__ im0, const float* __restrict__ flow,
    float* __restrict__ acc, float* __restrict__ wacc)
{
    int idx = blockIdx.x * BLK + threadIdx.x;
    if (idx >= BHW) return;
    int b = idx >> 20;           // HW = 1<<20
    int p = idx & (HW - 1);
    int y = p >> 10;             // Wn = 1<<10
    int x = p & (Wn - 1);

    float2 f = reinterpret_cast<const float2*>(flow)[idx];
    float X = (float)x + f.x;
    float Y = (float)y + f.y;
    float x0 = floorf(X), y0 = floorf(Y);

    float v0 = im0[(b * Cn + 0) * HW + p];
    float v1 = im0[(b * Cn + 1) * HW + p];
    float v2 = im0[(b * Cn + 2) * HW + p];

#pragma unroll
    for (int cy = 0; cy < 2; ++cy) {
#pragma unroll
        for (int cx = 0; cx < 2; ++cx) {
            float xi = x0 + (float)cx;
            float yi = y0 + (float)cy;
            if (xi < 0.f || xi > (float)(Wn - 1) ||
                yi < 0.f || yi > (float)(Hn - 1)) continue;
            float w = (1.f - fabsf(X - xi)) * (1.f - fabsf(Y - yi));
            int di = (int)yi * Wn + (int)xi;
            atomicAdd(&wacc[b * HW + di], w);
            atomicAdd(&acc[(b * Cn + 0) * HW + di], v0 * w);
            atomicAdd(&acc[(b * Cn + 1) * HW + di], v1 * w);
            atomicAdd(&acc[(b * Cn + 2) * HW + di], v2 * w);
        }
    }
}

// ------- infill iteration: dst = where(hole, gather(src,flowback), src) -----
__global__ __launch_bounds__(BLK) void infill_kernel(
    const float* __restrict__ src, const float* __restrict__ wacc,
    const float* __restrict__ flowback, float* __restrict__ dst,
    const int* __restrict__ n_iter, int iter)
{
    int n = *n_iter; if (n > MAX_ITERS) n = MAX_ITERS;
    if (iter >= n) return;

    int idx = blockIdx.x * BLK + threadIdx.x;
    if (idx >= BHW) return;
    int b = idx >> 20;
    int p = idx & (HW - 1);

    const float* sb = src + (size_t)b * Cn * HW;
    float o0, o1, o2;
    float wv = wacc[idx];
    if (wv != 0.f) {
        o0 = sb[p];
        o1 = sb[HW + p];
        o2 = sb[2 * HW + p];
    } else {
        int y = p >> 10, x = p & (Wn - 1);
        float2 f = reinterpret_cast<const float2*>(flowback)[idx];
        float X = (float)x + f.x;
        float Y = (float)y + f.y;
        float x0 = floorf(X), y0 = floorf(Y);
        o0 = o1 = o2 = 0.f;
#pragma unroll
        for (int cy = 0; cy < 2; ++cy) {
#pragma unroll
            for (int cx = 0; cx < 2; ++cx) {
                float xi = x0 + (float)cx;
                float yi = y0 + (float)cy;
                if (xi < 0.f || xi > (float)(Wn - 1) ||
                    yi < 0.f || yi > (float)(Hn - 1)) continue;
                float w = (1.f - fabsf(X - xi)) * (1.f - fabsf(Y - yi));
                int gi = (int)yi * Wn + (int)xi;
                o0 += sb[gi] * w;
                o1 += sb[HW + gi] * w;
                o2 += sb[2 * HW + gi] * w;
            }
        }
    }
    float* db = dst + (size_t)b * Cn * HW;
    db[p]          = o0;
    db[HW + p]     = o1;
    db[2 * HW + p] = o2;
}

// ------- if iteration count even (incl. 0), result sits in acc: copy out -----
__global__ __launch_bounds__(BLK) void copy_even_kernel(
    const float* __restrict__ A, float* __restrict__ dst,
    const int* __restrict__ n_iter)
{
    int n = *n_iter; if (n > MAX_ITERS) n = MAX_ITERS;
    if (n & 1) return;   // odd: result already in dst
    int i = blockIdx.x * BLK + threadIdx.x;
    if (i < BCHW) dst[i] = A[i];
}

extern "C" void kernel_launch(void* const* d_in, const int* in_sizes, int n_in,
                              void* d_out, int out_size, void* d_ws, size_t ws_size,
                              hipStream_t stream)
{
    const float* im0      = (const float*)d_in[0];
    const float* flow     = (const float*)d_in[1];
    const float* flowback = (const float*)d_in[2];
    const int*   n_iter   = (const int*)d_in[3];
    float* out  = (float*)d_out;
    float* acc  = (float*)d_ws;          // BCHW floats
    float* wacc = acc + BCHW;            // BHW floats

    // zero accumulators (64 MiB) — async memset is graph-capture safe
    hipMemsetAsync(d_ws, 0, (size_t)(BCHW + BHW) * sizeof(float), stream);

    int grid = (BHW + BLK - 1) / BLK;
    splat_kernel<<<grid, BLK, 0, stream>>>(im0, flow, acc, wacc);

    // ping-pong: iter 0: acc->out, iter 1: out->acc, ...
    for (int i = 0; i < MAX_ITERS; ++i) {
        const float* s = (i % 2 == 0) ? acc : out;
        float*       d = (i % 2 == 0) ? out : acc;
        infill_kernel<<<grid, BLK, 0, stream>>>(s, wacc, flowback, d, n_iter, i);
    }

    int grid2 = (BCHW + BLK - 1) / BLK;
    copy_even_kernel<<<grid2, BLK, 0, stream>>>(acc, out, n_iter);
}

// Round 2
// 427.961 us; speedup vs baseline: 6.4914x; 6.4914x over previous
//
#include <hip/hip_runtime.h>

#define BLK 256

constexpr int Bn = 4, Cn = 3, Hn = 1024, Wn = 1024;
constexpr int HW   = Hn * Wn;        // 1<<20
constexpr int BHW  = Bn * HW;        // 4,194,304
constexpr int BCHW = Bn * Cn * HW;   // 12,582,912
constexpr int MAX_ITERS = 4;

// dest-tile ownership splat
constexpr int TS  = 64;              // dest tile side
constexpr int Mg  = 24;              // source window margin
constexpr int WND = TS + 2 * Mg;     // 112
constexpr float FMAX = 23.0f;        // = Mg-1; owner handles |f|<=FMAX exactly

// ---------------- owner splat: no global atomics ----------------
// Each block owns a 64x64 dest tile; scans 112x112 source window; corners
// landing in the tile accumulate via LDS atomics; tile flushed with plain
// coalesced stores (exclusive writer per dest pixel). |flow|>FMAX excluded
// here and handled by splat_fallback (exact complement predicate).
__global__ __launch_bounds__(512) void splat_owner(
    const float* __restrict__ im0, const float* __restrict__ flow,
    float* __restrict__ acc, float* __restrict__ wacc)
{
    __shared__ float s[4][TS * TS];   // c0,c1,c2,w : 64 KiB
    const int bid  = blockIdx.x;
    const int b    = bid >> 8;        // 256 tiles per batch (16x16)
    const int tile = bid & 255;
    const int ty   = (tile >> 4) * TS;
    const int tx   = (tile & 15) * TS;

    for (int i = threadIdx.x; i < TS * TS; i += 512) {
        s[0][i] = 0.f; s[1][i] = 0.f; s[2][i] = 0.f; s[3][i] = 0.f;
    }
    __syncthreads();

    const float*  imb = im0 + (size_t)b * Cn * HW;
    const float2* flb = reinterpret_cast<const float2*>(flow) + (size_t)b * HW;

    for (int i = threadIdx.x; i < WND * WND; i += 512) {
        int wy = i / WND;
        int wx = i - wy * WND;
        int y = ty - Mg + wy;
        int x = tx - Mg + wx;
        if ((unsigned)y >= (unsigned)Hn || (unsigned)x >= (unsigned)Wn) continue;
        int p = (y << 10) + x;
        float2 f = flb[p];
        if (!(fabsf(f.x) <= FMAX && fabsf(f.y) <= FMAX)) continue;  // fallback's job
        float X = (float)x + f.x;
        float Y = (float)y + f.y;
        float x0 = floorf(X), y0 = floorf(Y);
        float v0 = imb[p], v1 = imb[HW + p], v2 = imb[2 * HW + p];
#pragma unroll
        for (int cy = 0; cy < 2; ++cy) {
#pragma unroll
            for (int cx = 0; cx < 2; ++cx) {
                float xi = x0 + (float)cx;
                float yi = y0 + (float)cy;
                int lx = (int)xi - tx;
                int ly = (int)yi - ty;
                if ((unsigned)lx >= (unsigned)TS || (unsigned)ly >= (unsigned)TS) continue;
                // weight arithmetic bitwise-identical to reference (hole mask!)
                float w = (1.f - fabsf(X - xi)) * (1.f - fabsf(Y - yi));
                int c = ly * TS + lx;
                atomicAdd(&s[0][c], v0 * w);
                atomicAdd(&s[1][c], v1 * w);
                atomicAdd(&s[2][c], v2 * w);
                atomicAdd(&s[3][c], w);
            }
        }
    }
    __syncthreads();

    float* accb = acc + (size_t)b * Cn * HW;
    float* wb   = wacc + (size_t)b * HW;
    for (int i = threadIdx.x; i < TS * TS; i += 512) {
        int ly = i >> 6, lx = i & 63;
        int p = ((ty + ly) << 10) + tx + lx;
        accb[p]          = s[0][i];
        accb[HW + p]     = s[1][i];
        accb[2 * HW + p] = s[2][i];
        wb[p]            = s[3][i];
    }
}

// ------- fallback: the rare |flow|>FMAX pixels, scattered atomics -------
__global__ __launch_bounds__(BLK) void splat_fallback(
    const float* __restrict__ im0, const float* __restrict__ flow,
    float* __restrict__ acc, float* __restrict__ wacc)
{
    int idx = blockIdx.x * BLK + threadIdx.x;
    if (idx >= BHW) return;
    float2 f = reinterpret_cast<const float2*>(flow)[idx];
    if (fabsf(f.x) <= FMAX && fabsf(f.y) <= FMAX) return;  // owner handled it

    int b = idx >> 20;
    int p = idx & (HW - 1);
    int y = p >> 10;
    int x = p & (Wn - 1);
    float X = (float)x + f.x;
    float Y = (float)y + f.y;
    float x0 = floorf(X), y0 = floorf(Y);
    float v0 = im0[(b * Cn + 0) * HW + p];
    float v1 = im0[(b * Cn + 1) * HW + p];
    float v2 = im0[(b * Cn + 2) * HW + p];
#pragma unroll
    for (int cy = 0; cy < 2; ++cy) {
#pragma unroll
        for (int cx = 0; cx < 2; ++cx) {
            float xi = x0 + (float)cx;
            float yi = y0 + (float)cy;
            if (xi < 0.f || xi > (float)(Wn - 1) ||
                yi < 0.f || yi > (float)(Hn - 1)) continue;
            float w = (1.f - fabsf(X - xi)) * (1.f - fabsf(Y - yi));
            int di = (int)yi * Wn + (int)xi;
            atomicAdd(&wacc[b * HW + di], w);
            atomicAdd(&acc[(b * Cn + 0) * HW + di], v0 * w);
            atomicAdd(&acc[(b * Cn + 1) * HW + di], v1 * w);
            atomicAdd(&acc[(b * Cn + 2) * HW + di], v2 * w);
        }
    }
}

// ------- infill iteration: dst = where(hole, gather(src,flowback), src) -----
__global__ __launch_bounds__(BLK) void infill_kernel(
    const float* __restrict__ src, const float* __restrict__ wacc,
    const float* __restrict__ flowback, float* __restrict__ dst,
    const int* __restrict__ n_iter, int iter)
{
    int n = *n_iter; if (n > MAX_ITERS) n = MAX_ITERS;
    if (iter >= n) return;

    int idx = blockIdx.x * BLK + threadIdx.x;
    if (idx >= BHW) return;
    int b = idx >> 20;
    int p = idx & (HW - 1);

    const float* sb = src + (size_t)b * Cn * HW;
    float o0, o1, o2;
    float wv = wacc[idx];
    if (wv != 0.f) {
        o0 = sb[p];
        o1 = sb[HW + p];
        o2 = sb[2 * HW + p];
    } else {
        int y = p >> 10, x = p & (Wn - 1);
        float2 f = reinterpret_cast<const float2*>(flowback)[idx];
        float X = (float)x + f.x;
        float Y = (float)y + f.y;
        float x0 = floorf(X), y0 = floorf(Y);
        o0 = o1 = o2 = 0.f;
#pragma unroll
        for (int cy = 0; cy < 2; ++cy) {
#pragma unroll
            for (int cx = 0; cx < 2; ++cx) {
                float xi = x0 + (float)cx;
                float yi = y0 + (float)cy;
                if (xi < 0.f || xi > (float)(Wn - 1) ||
                    yi < 0.f || yi > (float)(Hn - 1)) continue;
                float w = (1.f - fabsf(X - xi)) * (1.f - fabsf(Y - yi));
                int gi = (int)yi * Wn + (int)xi;
                o0 += sb[gi] * w;
                o1 += sb[HW + gi] * w;
                o2 += sb[2 * HW + gi] * w;
            }
        }
    }
    float* db = dst + (size_t)b * Cn * HW;
    db[p]          = o0;
    db[HW + p]     = o1;
    db[2 * HW + p] = o2;
}

// ------- if iteration count even (incl. 0), result sits in acc: copy out -----
__global__ __launch_bounds__(BLK) void copy_even_kernel(
    const float* __restrict__ A, float* __restrict__ dst,
    const int* __restrict__ n_iter)
{
    int n = *n_iter; if (n > MAX_ITERS) n = MAX_ITERS;
    if (n & 1) return;   // odd: result already in dst
    int i = blockIdx.x * BLK + threadIdx.x;
    if (i < BCHW) dst[i] = A[i];
}

extern "C" void kernel_launch(void* const* d_in, const int* in_sizes, int n_in,
                              void* d_out, int out_size, void* d_ws, size_t ws_size,
                              hipStream_t stream)
{
    const float* im0      = (const float*)d_in[0];
    const float* flow     = (const float*)d_in[1];
    const float* flowback = (const float*)d_in[2];
    const int*   n_iter   = (const int*)d_in[3];
    float* out  = (float*)d_out;
    float* acc  = (float*)d_ws;          // BCHW floats
    float* wacc = acc + BCHW;            // BHW floats

    // owner splat writes every acc/wacc element -> no memset needed
    int grid_owner = Bn * 256;           // 16x16 tiles of 64x64 per batch
    splat_owner<<<grid_owner, 512, 0, stream>>>(im0, flow, acc, wacc);

    int grid = (BHW + BLK - 1) / BLK;
    splat_fallback<<<grid, BLK, 0, stream>>>(im0, flow, acc, wacc);

    // ping-pong: iter 0: acc->out, iter 1: out->acc, ...
    for (int i = 0; i < MAX_ITERS; ++i) {
        const float* s = (i % 2 == 0) ? acc : out;
        float*       d = (i % 2 == 0) ? out : acc;
        infill_kernel<<<grid, BLK, 0, stream>>>(s, wacc, flowback, d, n_iter, i);
    }

    int grid2 = (BCHW + BLK - 1) / BLK;
    copy_even_kernel<<<grid2, BLK, 0, stream>>>(acc, out, n_iter);
}